// Round 16
// baseline (920.044 us; speedup 1.0000x reference)
//
#include <hip/hip_runtime.h>
#include <hip/hip_bf16.h>
#include <hip/hip_cooperative_groups.h>

namespace cg = cooperative_groups;

#define NN 12288
#define NE 196608
#define HD 128
#define ZD 128
#define NEGV (-1.0e9f)
#define SEG 16
#define GPREP (768 * 256)  // prep grid threads

using s8v = __attribute__((ext_vector_type(8))) short;  // 8 bf16 = 4 VGPRs
using f4v = __attribute__((ext_vector_type(4))) float;  // 4 fp32 acc
using i4v = __attribute__((ext_vector_type(4))) int;

__device__ __forceinline__ unsigned short f2bf(float f) {
    return __builtin_bit_cast(unsigned short, __float2bfloat16(f));
}
__device__ __forceinline__ float4 pack8(float4 a, float4 b) {
    unsigned p0 = ((unsigned)f2bf(a.y) << 16) | f2bf(a.x);
    unsigned p1 = ((unsigned)f2bf(a.w) << 16) | f2bf(a.z);
    unsigned p2 = ((unsigned)f2bf(b.y) << 16) | f2bf(b.x);
    unsigned p3 = ((unsigned)f2bf(b.w) << 16) | f2bf(b.z);
    i4v r = (i4v){(int)p0, (int)p1, (int)p2, (int)p3};
    return __builtin_bit_cast(float4, r);
}

struct PrepArgs {
    const int* esrc; const int* edst; const int* ndep;
    const float* x; const float* z;
    const float* W1; const float* b1;
    const float* W2; const float* b2;
    const float* Wm1; const float* bm1;
    const float* Wm2; const float* bm2;
    const float* Wsm; const float* Wtm;
    const float* Wi1; const float* bi1;
    int* degi; int* cnt; float* inv; float* agg2;
    float* cz1; float* cz2;
    int* offs; int* cursor; int* bofs; int* dcur;
    int* sidx; int* sdep; int* prank;
    int* ebsrc; float* ebw;
    __hip_bfloat16* wt7;
    unsigned short* h1b; float* aggH;
    float* outA; float* outB;
    __hip_bfloat16* htb; __hip_bfloat16* hsb;
};

// ===== macros shared by mlp7 phase =====
#define AFRAGS(BUF) \
    s8v a0_ = __builtin_bit_cast(s8v, (BUF)[lane16 * 16 + ((quad     ) ^ lane16)]); \
    s8v a1_ = __builtin_bit_cast(s8v, (BUF)[lane16 * 16 + ((quad +  4) ^ lane16)]); \
    s8v a2_ = __builtin_bit_cast(s8v, (BUF)[lane16 * 16 + ((quad +  8) ^ lane16)]); \
    s8v a3_ = __builtin_bit_cast(s8v, (BUF)[lane16 * 16 + ((quad + 12) ^ lane16)]);

#define NBACC(WT4, NCOL, ACC) \
    f4v ACC = (f4v){0.f, 0.f, 0.f, 0.f}; \
    ACC = __builtin_amdgcn_mfma_f32_16x16x32_bf16(a0_, __builtin_bit_cast(s8v, (WT4)[(NCOL) * 16 + quad     ]), ACC, 0, 0, 0); \
    ACC = __builtin_amdgcn_mfma_f32_16x16x32_bf16(a1_, __builtin_bit_cast(s8v, (WT4)[(NCOL) * 16 + quad +  4]), ACC, 0, 0, 0); \
    ACC = __builtin_amdgcn_mfma_f32_16x16x32_bf16(a2_, __builtin_bit_cast(s8v, (WT4)[(NCOL) * 16 + quad +  8]), ACC, 0, 0, 0); \
    ACC = __builtin_amdgcn_mfma_f32_16x16x32_bf16(a3_, __builtin_bit_cast(s8v, (WT4)[(NCOL) * 16 + quad + 12]), ACC, 0, 0, 0);

#define BST(EXPR, RR, COL, USPTR) { int rw_ = quad * 4 + (RR); int cc_ = (COL) >> 3; \
    (USPTR)[rw_ * 128 + (((cc_ ^ rw_)) << 3) + ((COL) & 7)] = f2bf(EXPR); }

#define LDS4R(ACC, B, COL, US) \
    BST(fmaxf(ACC[0] + (B), 0.f), 0, COL, US) BST(fmaxf(ACC[1] + (B), 0.f), 1, COL, US) \
    BST(fmaxf(ACC[2] + (B), 0.f), 2, COL, US) BST(fmaxf(ACC[3] + (B), 0.f), 3, COL, US)

#define LDS4(ACC, B, COL, US) \
    BST(ACC[0] + (B), 0, COL, US) BST(ACC[1] + (B), 1, COL, US) \
    BST(ACC[2] + (B), 2, COL, US) BST(ACC[3] + (B), 3, COL, US)

#define GBF4S(ACC, COL, PTR) \
    ((unsigned short*)(PTR))[(size_t)pr0 * HD + (COL)] = f2bf(ACC[0]); \
    ((unsigned short*)(PTR))[(size_t)pr1 * HD + (COL)] = f2bf(ACC[1]); \
    ((unsigned short*)(PTR))[(size_t)pr2 * HD + (COL)] = f2bf(ACC[2]); \
    ((unsigned short*)(PTR))[(size_t)pr3 * HD + (COL)] = f2bf(ACC[3]);

#define GF4(ACC, B, COL, PTR) \
    (PTR)[(size_t)(r0 + quad * 4 + 0) * HD + (COL)] = ACC[0] + (B); \
    (PTR)[(size_t)(r0 + quad * 4 + 1) * HD + (COL)] = ACC[1] + (B); \
    (PTR)[(size_t)(r0 + quad * 4 + 2) * HD + (COL)] = ACC[2] + (B); \
    (PTR)[(size_t)(r0 + quad * 4 + 3) * HD + (COL)] = ACC[3] + (B);

// ===== ONE cooperative kernel: zero -> counts/wtrans/zvec -> prefix ->
// bucket/sort -> gather2 -> lin1 -> gatherH -> mlp7.  768 blocks x 256
// (3 blocks/CU co-resident), 7 grid.sync()s replace 7 kernel launches.
__global__ __launch_bounds__(256, 3) void k_prep(PrepArgs p) {
    cg::grid_group grid = cg::this_grid();
    __shared__ float4 bufA4[256];  // 4 KB (mlp7 ping) ; aliased by prefix scan
    __shared__ float4 bufB4[256];  // 4 KB (mlp7 pong)
    int tid = threadIdx.x;
    int bid = blockIdx.x;
    int gid = bid * 256 + tid;  // < GPREP = 196608

    // P0: zero degi + cnt
    if (gid < NN + 64) {
        if (gid < NN) p.degi[gid] = 0;
        else p.cnt[gid - NN] = 0;
    }
    grid.sync();

    // P1: edge in-degree count + depth count + 7x W^T transpose + cz1/cz2
    for (int flat = gid; flat < NE + NN + 7 * 16384 + 256; flat += GPREP) {
        if (flat < NE) {
            atomicAdd(&p.degi[p.edst[flat]], 1);
        } else if (flat < NE + NN) {
            atomicAdd(&p.cnt[p.ndep[flat - NE]], 1);
        } else if (flat < NE + NN + 7 * 16384) {
            int f = flat - NE - NN;
            int g = f >> 14;
            int rem = f & 16383;
            int k = rem >> 7, n = rem & 127;
            const float* src;
            if (g == 0) src = p.W2;
            else if (g == 1) src = p.Wm1;
            else if (g == 2) src = p.Wm2;
            else if (g == 3) src = p.Wtm;
            else if (g == 4) src = p.Wsm;
            else if (g == 5) src = p.Wi1;
            else src = p.Wi1 + 128 * HD;
            p.wt7[(g << 14) + n * 128 + k] = __float2bfloat16(src[rem]);
        } else {
            int f = flat - NE - NN - 7 * 16384;  // 0..255
            int j = f & 127;
            const float* W = (f < 128) ? (p.Wm1 + HD * HD) : (p.Wi1 + 2 * HD * HD);
            float A0 = 0.f, A1 = 0.f, A2 = 0.f, A3 = 0.f;
            for (int k = 0; k < ZD; k += 4) {
                A0 = fmaf(p.z[k],     W[(k    ) * HD + j], A0);
                A1 = fmaf(p.z[k + 1], W[(k + 1) * HD + j], A1);
                A2 = fmaf(p.z[k + 2], W[(k + 2) * HD + j], A2);
                A3 = fmaf(p.z[k + 3], W[(k + 3) * HD + j], A3);
            }
            float r = (A0 + A1) + (A2 + A3);
            if (f < 128) p.cz1[j] = r + p.bm1[j];
            else         p.cz2[j] = r + p.bi1[j];
        }
    }
    grid.sync();

    // P2: CSR prefix + inv + agg2 self term + depth-bucket scan (block 0)
    if (bid == 0) {
        int* part = (int*)bufA4;
        int base = tid * 48;
        int s = 0;
        for (int k = 0; k < 48; ++k) s += p.degi[base + k];
        part[tid] = s;
        __syncthreads();
        for (int off = 1; off < 256; off <<= 1) {
            int v = (tid >= off) ? part[tid - off] : 0;
            __syncthreads();
            part[tid] += v;
            __syncthreads();
        }
        int run = part[tid] - s;  // exclusive
        for (int k = 0; k < 48; ++k) {
            int i = base + k;
            int d = p.degi[i];
            p.offs[i] = run;
            p.cursor[i] = run;
            run += d;
            float iv = rsqrtf((float)(d + 1));
            p.inv[i] = iv;
            float w = iv * iv;
            p.agg2[2 * i]     = p.x[2 * i] * w;
            p.agg2[2 * i + 1] = p.x[2 * i + 1] * w;
        }
        if (tid == 255) p.offs[NN] = run;
        if (tid == 0) {
            int r = 0;
            for (int d = 0; d < 64; ++d) {
                p.bofs[d] = r;
                p.dcur[d] = r;
                r += p.cnt[d];
            }
            p.bofs[64] = r;
        }
    }
    grid.sync();

    // P3: edge bucketing + depth-sort scatter
    for (int flat = gid; flat < NE + NN; flat += GPREP) {
        if (flat < NE) {
            int u = p.esrc[flat], v = p.edst[flat];
            int pos = atomicAdd(&p.cursor[v], 1);
            p.ebsrc[pos] = u;
            p.ebw[pos] = p.inv[u] * p.inv[v];
        } else {
            int v = flat - NE;
            int d = p.ndep[v];
            int q = atomicAdd(&p.dcur[d], 1);
            p.sidx[q] = v;
            p.sdep[q] = d;
            p.prank[v] = q;
        }
    }
    grid.sync();

    // P4: layer-1 aggregation (gather, thread per node)
    if (gid < NN) {
        int v = gid;
        float ax = p.agg2[2 * v], ay = p.agg2[2 * v + 1];
        int b = p.offs[v], e = p.offs[v + 1];
        const float2* X2 = (const float2*)p.x;
        int k = b;
        for (; k + 4 <= e; k += 4) {
            int u0 = p.ebsrc[k], u1 = p.ebsrc[k + 1], u2 = p.ebsrc[k + 2], u3 = p.ebsrc[k + 3];
            float w0 = p.ebw[k], w1 = p.ebw[k + 1], w2 = p.ebw[k + 2], w3 = p.ebw[k + 3];
            float2 x0 = X2[u0], x1 = X2[u1], x2 = X2[u2], x3 = X2[u3];
            ax = fmaf(x0.x, w0, ax); ay = fmaf(x0.y, w0, ay);
            ax = fmaf(x1.x, w1, ax); ay = fmaf(x1.y, w1, ay);
            ax = fmaf(x2.x, w2, ax); ay = fmaf(x2.y, w2, ay);
            ax = fmaf(x3.x, w3, ax); ay = fmaf(x3.y, w3, ay);
        }
        for (; k < e; ++k) {
            int u = p.ebsrc[k];
            float w = p.ebw[k];
            float2 xv = X2[u];
            ax = fmaf(xv.x, w, ax);
            ay = fmaf(xv.y, w, ay);
        }
        p.agg2[2 * v] = ax;
        p.agg2[2 * v + 1] = ay;
    }
    grid.sync();

    // P5: h1(bf16) = relu(agg2 @ W1 + b1); seed aggH self term
    for (int t = gid; t < NN * HD; t += GPREP) {
        int v = t >> 7, j = t & 127;
        float hv = fmaxf(fmaf(p.agg2[2 * v], p.W1[j],
                         fmaf(p.agg2[2 * v + 1], p.W1[HD + j], p.b1[j])), 0.f);
        p.h1b[t] = f2bf(hv);
        float iv = p.inv[v];
        p.aggH[t] = hv * iv * iv;
    }
    grid.sync();

    // P6: layer-2 aggregation — one wave per node, 4 nodes/wave, bf16 rows
    {
        int lane = tid & 63;
        int wvid = bid * 4 + (tid >> 6);  // 3072 waves
        const unsigned* H1 = (const unsigned*)p.h1b;
        float2* A2 = (float2*)p.aggH;
        for (int i = 0; i < 4; ++i) {
            int v = wvid * 4 + i;
            float2 acc = A2[(size_t)v * 64 + lane];
            int b = p.offs[v], e = p.offs[v + 1];
            int k = b;
            for (; k + 4 <= e; k += 4) {
                int u0 = p.ebsrc[k], u1 = p.ebsrc[k + 1], u2 = p.ebsrc[k + 2], u3 = p.ebsrc[k + 3];
                float w0 = p.ebw[k], w1 = p.ebw[k + 1], w2 = p.ebw[k + 2], w3 = p.ebw[k + 3];
                unsigned hb0 = H1[(size_t)u0 * 64 + lane];
                unsigned hb1 = H1[(size_t)u1 * 64 + lane];
                unsigned hb2 = H1[(size_t)u2 * 64 + lane];
                unsigned hb3 = H1[(size_t)u3 * 64 + lane];
                acc.x = fmaf(__builtin_bit_cast(float, hb0 << 16), w0, acc.x);
                acc.y = fmaf(__builtin_bit_cast(float, hb0 & 0xFFFF0000u), w0, acc.y);
                acc.x = fmaf(__builtin_bit_cast(float, hb1 << 16), w1, acc.x);
                acc.y = fmaf(__builtin_bit_cast(float, hb1 & 0xFFFF0000u), w1, acc.y);
                acc.x = fmaf(__builtin_bit_cast(float, hb2 << 16), w2, acc.x);
                acc.y = fmaf(__builtin_bit_cast(float, hb2 & 0xFFFF0000u), w2, acc.y);
                acc.x = fmaf(__builtin_bit_cast(float, hb3 << 16), w3, acc.x);
                acc.y = fmaf(__builtin_bit_cast(float, hb3 & 0xFFFF0000u), w3, acc.y);
            }
            for (; k < e; ++k) {
                int u = p.ebsrc[k];
                float w = p.ebw[k];
                unsigned hb = H1[(size_t)u * 64 + lane];
                acc.x = fmaf(__builtin_bit_cast(float, hb << 16), w, acc.x);
                acc.y = fmaf(__builtin_bit_cast(float, hb & 0xFFFF0000u), w, acc.y);
            }
            A2[(size_t)v * 64 + lane] = acc;
        }
    }
    grid.sync();

    // P7: fused 7-GEMM MLP chain on MFMA (r0 = bid*16; exactly 768 blocks)
    {
        int wv = tid >> 6;
        int l = tid & 63;
        int lane16 = l & 15;
        int quad = l >> 4;
        int r0 = bid * 16;
        const float4* wt4 = (const float4*)p.wt7;

        int pr0 = p.prank[r0 + quad * 4 + 0];
        int pr1 = p.prank[r0 + quad * 4 + 1];
        int pr2 = p.prank[r0 + quad * 4 + 2];
        int pr3 = p.prank[r0 + quad * 4 + 3];

        __syncthreads();  // bufA4 reuse after prefix scan (block 0)
        {
            const float4* g4 = (const float4*)(p.aggH + (size_t)r0 * HD);
            float4 u0 = g4[2 * tid], u1 = g4[2 * tid + 1];
            int row_ = tid >> 4, c_ = tid & 15;
            bufA4[row_ * 16 + (c_ ^ row_)] = pack8(u0, u1);
        }
        __syncthreads();
        int col0 = wv * 32 + lane16, col1 = col0 + 16;
        unsigned short* usA = (unsigned short*)bufA4;
        unsigned short* usB = (unsigned short*)bufB4;

        {   // G1: h2 = relu(aggH @ W2 + b2) -> bufB
            AFRAGS(bufA4)
            NBACC(wt4, col0, cA) NBACC(wt4, col1, cB)
            float q0 = p.b2[col0], q1 = p.b2[col1];
            LDS4R(cA, q0, col0, usB) LDS4R(cB, q1, col1, usB)
        }
        __syncthreads();
        {   // G2: t = relu(h2 @ Wm1 + cz1) -> bufA
            AFRAGS(bufB4)
            const float4* wt = wt4 + 2048;
            NBACC(wt, col0, cA) NBACC(wt, col1, cB)
            float q0 = p.cz1[col0], q1 = p.cz1[col1];
            LDS4R(cA, q0, col0, usA) LDS4R(cB, q1, col1, usA)
        }
        __syncthreads();
        {   // G3: h = t @ Wm2 + bm2 -> bufB
            AFRAGS(bufA4)
            const float4* wt = wt4 + 2 * 2048;
            NBACC(wt, col0, cA) NBACC(wt, col1, cB)
            float q0 = p.bm2[col0], q1 = p.bm2[col1];
            LDS4(cA, q0, col0, usB) LDS4(cB, q1, col1, usB)
        }
        __syncthreads();
        {   // G4: ht -> sorted rows, bf16
            AFRAGS(bufB4)
            const float4* wt = wt4 + 3 * 2048;
            NBACC(wt, col0, cA) NBACC(wt, col1, cB)
            GBF4S(cA, col0, p.htb) GBF4S(cB, col1, p.htb)
        }
        {   // G5: hs -> sorted rows, bf16
            AFRAGS(bufB4)
            const float4* wt = wt4 + 4 * 2048;
            NBACC(wt, col0, cA) NBACC(wt, col1, cB)
            GBF4S(cA, col0, p.hsb) GBF4S(cB, col1, p.hsb)
        }
        {   // G6: A = h @ Wi1[:128] -> f32
            AFRAGS(bufB4)
            const float4* wt = wt4 + 5 * 2048;
            NBACC(wt, col0, cA) NBACC(wt, col1, cB)
            GF4(cA, 0.f, col0, p.outA) GF4(cB, 0.f, col1, p.outA)
        }
        {   // G7: B = h @ Wi1[128:256] + cz2 -> f32 (in-place over aggH)
            AFRAGS(bufB4)
            const float4* wt = wt4 + 6 * 2048;
            NBACC(wt, col0, cA) NBACC(wt, col1, cB)
            float q0 = p.cz2[col0], q1 = p.cz2[col1];
            GF4(cA, q0, col0, p.outB) GF4(cB, q1, col1, p.outB)
        }
    }
}

// ===== Fused bf16-MFMA scores + masked top-2 (r15-proven, v8.2) =====
// Heavy row-blocks (large valid prefix) launched FIRST (reversed blockIdx.x)
// for better makespan. pv stores packed scores only.
#define STG(buf, q, val) { int r_ = (q) >> 4, c_ = (q) & 15; \
    (buf)[r_ * 16 + (c_ ^ (r_ & 7))] = (val); }

#define DO_KC(kc, AR) { \
    int co_ = (kc) * 4 + quad; \
    int bo_ = bbase + (co_ ^ brm); \
    acc0 = __builtin_amdgcn_mfma_f32_16x16x32_bf16(AR, __builtin_bit_cast(s8v, B[bo_      ]), acc0, 0, 0, 0); \
    acc1 = __builtin_amdgcn_mfma_f32_16x16x32_bf16(AR, __builtin_bit_cast(s8v, B[bo_ + 256]), acc1, 0, 0, 0); \
    acc2 = __builtin_amdgcn_mfma_f32_16x16x32_bf16(AR, __builtin_bit_cast(s8v, B[bo_ + 512]), acc2, 0, 0, 0); \
    acc3 = __builtin_amdgcn_mfma_f32_16x16x32_bf16(AR, __builtin_bit_cast(s8v, B[bo_ + 768]), acc3, 0, 0, 0); }

#define ROW_MERGE(r, accel) { \
    unsigned pb_ = (__builtin_bit_cast(unsigned, accel) & 0xFFFFC000u) | e_; \
    float sf_ = __builtin_bit_cast(float, (du_ < dvr##r) ? pb_ : negp_); \
    k2_##r = __builtin_amdgcn_fmed3f(k1_##r, k2_##r, sf_); \
    k1_##r = fmaxf(k1_##r, sf_); }

#define DO_MERGE(nb, accv) { \
    int p_ = u0 + (nb) * 16 + lane16; \
    int du_ = sdep[p_]; \
    unsigned e_ = 0x3FFFu - (unsigned)sidx[p_]; \
    unsigned negp_ = negbase | e_; \
    ROW_MERGE(0, accv[0]) ROW_MERGE(1, accv[1]) \
    ROW_MERGE(2, accv[2]) ROW_MERGE(3, accv[3]) }

#define BF(r, m) { \
    float o1_ = __shfl_xor(k1_##r, m, 64); \
    float o2_ = __shfl_xor(k2_##r, m, 64); \
    float m2_ = fmaxf(k2_##r, o2_); \
    k2_##r = __builtin_amdgcn_fmed3f(k1_##r, o1_, m2_); \
    k1_##r = fmaxf(k1_##r, o1_); }

#define EMITR(r, GROW) { \
    size_t o = ((size_t)seg * NN + (GROW)) * 2; \
    pv[o] = k1_##r; pv[o + 1] = k2_##r; }

__global__ __launch_bounds__(256) void k_score_top2_mfma(
        const __hip_bfloat16* __restrict__ htb,
        const __hip_bfloat16* __restrict__ hsb,
        const int* __restrict__ sdep, const int* __restrict__ sidx,
        const int* __restrict__ bofs,
        float* __restrict__ pv) {
    __shared__ float4 Bs4[2][64 * 16];   // 32 KB double buffer (B only)
    int tid = threadIdx.x;
    int w = tid >> 6;
    int l = tid & 63;
    int lane16 = l & 15;
    int quad = l >> 4;
    int rb = (int)gridDim.x - 1 - (int)blockIdx.x;  // heavy blocks first
    int row0 = rb * 64;
    int seg = blockIdx.y;
    const unsigned negbase = __builtin_bit_cast(unsigned, NEGV) & 0xFFFFC000u;

    // even-split of this row-block's valid candidate prefix
    int dmax = sdep[row0 + 63];
    int lim = bofs[dmax];
    int nt = (lim + 63) >> 6;               // total tiles, <= 192
    int t0 = (seg * nt) >> 4;
    int t1 = ((seg + 1) * nt) >> 4;

    // A fragments: named registers, loaded once (sorted target rows).
    s8v ar0, ar1, ar2, ar3;
    {
        const float4* ga = (const float4*)(htb + (size_t)(row0 + w * 16 + lane16) * HD);
        ar0 = __builtin_bit_cast(s8v, ga[quad]);
        ar1 = __builtin_bit_cast(s8v, ga[4 + quad]);
        ar2 = __builtin_bit_cast(s8v, ga[8 + quad]);
        ar3 = __builtin_bit_cast(s8v, ga[12 + quad]);
    }
    if (t0 < t1) {   // stage first tile into the parity-matching buffer
        float4* B0 = Bs4[t0 & 1];
        const float4* gb = (const float4*)(hsb + (size_t)(t0 * 64) * HD);
        float4 b0_ = gb[tid], b1_ = gb[tid + 256], b2_ = gb[tid + 512], b3_ = gb[tid + 768];
        STG(B0, tid, b0_) STG(B0, tid + 256, b1_)
        STG(B0, tid + 512, b2_) STG(B0, tid + 768, b3_)
    }

    int bbase = lane16 * 16, brm = lane16 & 7;

    int dvr0 = sdep[row0 + w * 16 + quad * 4 + 0];
    int dvr1 = sdep[row0 + w * 16 + quad * 4 + 1];
    int dvr2 = sdep[row0 + w * 16 + quad * 4 + 2];
    int dvr3 = sdep[row0 + w * 16 + quad * 4 + 3];

    // defaults: packed NEGV for orig u=0 (k1) and u=1 (k2), lane16==0 only.
    float ki1 = (lane16 == 0) ? __builtin_bit_cast(float, negbase | 0x3FFFu) : -3.4e38f;
    float ki2 = (lane16 == 0) ? __builtin_bit_cast(float, negbase | 0x3FFEu) : -3.4e38f;
    float k1_0 = ki1, k1_1 = ki1, k1_2 = ki1, k1_3 = ki1;
    float k2_0 = ki2, k2_1 = ki2, k2_2 = ki2, k2_3 = ki2;

    float4 p0, p1, p2, p3;
    for (int t = t0; t < t1; ++t) {
        int u0 = t * 64;
        __syncthreads();
        if (t + 1 < t1) {
            const float4* g = (const float4*)(hsb + (size_t)(u0 + 64) * HD);
            p0 = g[tid]; p1 = g[tid + 256]; p2 = g[tid + 512]; p3 = g[tid + 768];
        }
        const float4* B = Bs4[t & 1];
        f4v acc0 = (f4v){0.f, 0.f, 0.f, 0.f};
        f4v acc1 = (f4v){0.f, 0.f, 0.f, 0.f};
        f4v acc2 = (f4v){0.f, 0.f, 0.f, 0.f};
        f4v acc3 = (f4v){0.f, 0.f, 0.f, 0.f};
        DO_KC(0, ar0) DO_KC(1, ar1) DO_KC(2, ar2) DO_KC(3, ar3)
        DO_MERGE(0, acc0) DO_MERGE(1, acc1) DO_MERGE(2, acc2) DO_MERGE(3, acc3)
        if (t + 1 < t1) {
            float4* Bn = Bs4[(t + 1) & 1];
            STG(Bn, tid, p0) STG(Bn, tid + 256, p1)
            STG(Bn, tid + 512, p2) STG(Bn, tid + 768, p3)
        }
    }

    BF(0, 1) BF(1, 1) BF(2, 1) BF(3, 1)
    BF(0, 2) BF(1, 2) BF(2, 2) BF(3, 2)
    BF(0, 4) BF(1, 4) BF(2, 4) BF(3, 4)
    BF(0, 8) BF(1, 8) BF(2, 8) BF(3, 8)

    if (lane16 == 0) {
        int g0 = sidx[row0 + w * 16 + quad * 4 + 0];
        int g1 = sidx[row0 + w * 16 + quad * 4 + 1];
        int g2 = sidx[row0 + w * 16 + quad * 4 + 2];
        int g3 = sidx[row0 + w * 16 + quad * 4 + 3];
        EMITR(0, g0) EMITR(1, g1) EMITR(2, g2) EMITR(3, g3)
    }
}

// ONE kernel writes ALL outputs (f32): parallel packed merge (r15-proven).
__global__ __launch_bounds__(256) void k_final(const float* __restrict__ pv,
                                               const int* __restrict__ ntype,
                                               const int* __restrict__ ndepth,
                                               const float* __restrict__ A,
                                               const float* __restrict__ B,
                                               const float* __restrict__ Wi2,
                                               const float* __restrict__ bi2,
                                               float* __restrict__ out) {
    int tid = threadIdx.x;
    int lane = tid & 63;
    int v = blockIdx.x * 4 + (tid >> 6);

    float k1 = -3.4e38f;
    if (lane < 32) {
        k1 = pv[((size_t)(lane >> 1) * NN + v) * 2 + (lane & 1)];
    }
    float k2 = -3.4e38f;
#pragma unroll
    for (int m = 1; m <= 16; m <<= 1) {
        float o1 = __shfl_xor(k1, m, 64);
        float o2 = __shfl_xor(k2, m, 64);
        float m2 = fmaxf(k2, o2);
        k2 = __builtin_amdgcn_fmed3f(k1, o1, m2);
        k1 = fmaxf(k1, o1);
    }
    float K1 = __shfl(k1, 0, 64);
    float K2 = __shfl(k2, 0, 64);
    unsigned b1 = __builtin_bit_cast(unsigned, K1);
    unsigned b2 = __builtin_bit_cast(unsigned, K2);
    int I1 = 0x3FFF - (int)(b1 & 0x3FFFu);
    int I2 = 0x3FFF - (int)(b2 & 0x3FFFu);

    if (lane == 0) {
        int tp = ntype[v];
        bool tv = (tp != 0) && (ndepth[v] > 0) && (K1 > -5.0e8f);  // NEG/2
        out[2 * NN + 2 * v]     = K1;
        out[2 * NN + 2 * v + 1] = K2;
        out[4 * NN + 2 * v]     = (float)I1;
        out[4 * NN + 2 * v + 1] = (float)I2;
        out[6 * NN + 2 * v]     = tv ? 1.f : 0.f;
        out[6 * NN + 2 * v + 1] = (tv && tp == 2) ? 1.f : 0.f;
    }

    int u1 = min(max(I1, 0), NN - 1);
    int u2 = min(max(I2, 0), NN - 1);
    const float2* A2p = (const float2*)A;
    float2 av1 = A2p[(size_t)u1 * 64 + lane];
    float2 av2 = A2p[(size_t)u2 * 64 + lane];
    float2 bv = ((const float2*)B)[(size_t)v * 64 + lane];
    float2 wv = ((const float2*)Wi2)[lane];
    float bias = bi2[0];
    float a1 = fmaf(fmaxf(av1.x + bv.x, 0.f), wv.x,
                    fmaxf(av1.y + bv.y, 0.f) * wv.y);
    float a2 = fmaf(fmaxf(av2.x + bv.x, 0.f), wv.x,
                    fmaxf(av2.y + bv.y, 0.f) * wv.y);
#pragma unroll
    for (int off = 32; off > 0; off >>= 1) {
        a1 += __shfl_down(a1, off);
        a2 += __shfl_down(a2, off);
    }
    if (lane == 0) {
        out[2 * v]     = 1.f / (1.f + expf(-(a1 + bias)));
        out[2 * v + 1] = 1.f / (1.f + expf(-(a2 + bias)));
    }
}

extern "C" void kernel_launch(void* const* d_in, const int* in_sizes, int n_in,
                              void* d_out, int out_size, void* d_ws, size_t ws_size,
                              hipStream_t stream) {
    (void)in_sizes; (void)n_in; (void)out_size; (void)ws_size;
    const float* x   = (const float*)d_in[0];
    const float* z   = (const float*)d_in[1];
    const int* ntype = (const int*)d_in[2];
    const int* ndep  = (const int*)d_in[3];
    const int* eidx  = (const int*)d_in[4];
    const float* W1  = (const float*)d_in[5];
    const float* b1  = (const float*)d_in[6];
    const float* W2  = (const float*)d_in[7];
    const float* b2  = (const float*)d_in[8];
    const float* Wm1 = (const float*)d_in[9];
    const float* bm1 = (const float*)d_in[10];
    const float* Wm2 = (const float*)d_in[11];
    const float* bm2 = (const float*)d_in[12];
    const float* Wsm = (const float*)d_in[13];
    const float* Wtm = (const float*)d_in[14];
    const float* Wi1 = (const float*)d_in[15];
    const float* bi1 = (const float*)d_in[16];
    const float* Wi2 = (const float*)d_in[17];
    const float* bi2 = (const float*)d_in[18];
    float* out = (float*)d_out;

    const int* esrc = eidx;
    const int* edst = eidx + NE;

    // Workspace layout (~24.5 MiB).
    const size_t S2N = (size_t)SEG * 2 * NN;  // 393216
    float* ws = (float*)d_ws;
    float* pv     = ws;                       // [S2N] f (packed scores)
    int*   pi     = (int*)(pv + S2N);         // [S2N] i (spacer)
    int*   degi   = pi + S2N;                 // [NN]
    int*   cnt    = degi + NN;                // [64]
    float* inv    = (float*)(cnt + 64);       // [NN]
    float* agg2   = inv + NN;                 // [2NN]
    float* cz1    = agg2 + 2 * NN;            // [128]
    float* cz2    = cz1 + 128;                // [128]
    int*   offs   = (int*)(cz2 + 128);        // [NN+16]
    int*   cursor = offs + NN + 16;           // [NN]
    int*   bofs   = cursor + NN;              // [80]
    int*   dcur   = bofs + 80;                // [64]
    int*   sidx   = dcur + 64;                // [NN]
    int*   sdep   = sidx + NN;                // [NN]
    int*   prank  = sdep + NN;                // [NN]
    int*   ebsrc  = prank + NN;               // [NE]
    float* ebw    = (float*)(ebsrc + NE);     // [NE]
    __hip_bfloat16* wt7 = (__hip_bfloat16*)(ebw + NE);  // [7*16384] bf16
    size_t F = (size_t)NN * HD;
    float* s0 = (float*)(wt7 + 7 * 16384);    // h1b (bf16) -> {htb_s, hsb_s}
    float* s1 = s0 + F;                       // aggH -> B (in-place)
    float* s2 = s1 + F;                       // A
    unsigned short* h1b = (unsigned short*)s0;
    __hip_bfloat16* htb = (__hip_bfloat16*)s0;
    __hip_bfloat16* hsb = htb + F;

    PrepArgs pa;
    pa.esrc = esrc; pa.edst = edst; pa.ndep = ndep;
    pa.x = x; pa.z = z;
    pa.W1 = W1; pa.b1 = b1; pa.W2 = W2; pa.b2 = b2;
    pa.Wm1 = Wm1; pa.bm1 = bm1; pa.Wm2 = Wm2; pa.bm2 = bm2;
    pa.Wsm = Wsm; pa.Wtm = Wtm; pa.Wi1 = Wi1; pa.bi1 = bi1;
    pa.degi = degi; pa.cnt = cnt; pa.inv = inv; pa.agg2 = agg2;
    pa.cz1 = cz1; pa.cz2 = cz2;
    pa.offs = offs; pa.cursor = cursor; pa.bofs = bofs; pa.dcur = dcur;
    pa.sidx = sidx; pa.sdep = sdep; pa.prank = prank;
    pa.ebsrc = ebsrc; pa.ebw = ebw;
    pa.wt7 = wt7;
    pa.h1b = h1b; pa.aggH = s1;
    pa.outA = s2; pa.outB = s1;
    pa.htb = htb; pa.hsb = hsb;

    void* kargs[] = { (void*)&pa };
    hipLaunchCooperativeKernel((const void*)k_prep, dim3(768), dim3(256),
                               kargs, 0, stream);
    k_score_top2_mfma<<<dim3(NN / 64, SEG), 256, 0, stream>>>(
        htb, hsb, sdep, sidx, bofs, pv);
    k_final<<<NN / 4, 256, 0, stream>>>(pv, ntype, ndep, s2, s1, Wi2, bi2, out);
}

// Round 17
// 282.734 us; speedup vs baseline: 3.2541x; 3.2541x over previous
//
#include <hip/hip_runtime.h>
#include <hip/hip_bf16.h>

#define NN 12288
#define NE 196608
#define HD 128
#define ZD 128
#define NEGV (-1.0e9f)
#define SEG 16

using s8v = __attribute__((ext_vector_type(8))) short;  // 8 bf16 = 4 VGPRs
using f4v = __attribute__((ext_vector_type(4))) float;  // 4 fp32 acc
using i4v = __attribute__((ext_vector_type(4))) int;

__device__ __forceinline__ unsigned short f2bf(float f) {
    return __builtin_bit_cast(unsigned short, __float2bfloat16(f));
}
__device__ __forceinline__ float4 pack8(float4 a, float4 b) {
    unsigned p0 = ((unsigned)f2bf(a.y) << 16) | f2bf(a.x);
    unsigned p1 = ((unsigned)f2bf(a.w) << 16) | f2bf(a.z);
    unsigned p2 = ((unsigned)f2bf(b.y) << 16) | f2bf(b.x);
    unsigned p3 = ((unsigned)f2bf(b.w) << 16) | f2bf(b.z);
    i4v r = (i4v){(int)p0, (int)p1, (int)p2, (int)p3};
    return __builtin_bit_cast(float4, r);
}

// Mega split-grid of INDEPENDENT prep work:
// [0,768): edge in-degree count; [768,816): depth-bucket count;
// [816,1264): 7x weight transpose to bf16 W^T; [1264]: cz1/cz2.
__global__ __launch_bounds__(256) void k_counts_wz(
        const int* __restrict__ edst, const int* __restrict__ ndep,
        const float* __restrict__ W2, const float* __restrict__ Wm1,
        const float* __restrict__ Wm2, const float* __restrict__ Wtm,
        const float* __restrict__ Wsm, const float* __restrict__ Wi1,
        const float* __restrict__ z, const float* __restrict__ bm1,
        const float* __restrict__ bi1,
        int* degi, int* cnt, __hip_bfloat16* __restrict__ wt7,
        float* cz1, float* cz2) {
    int tid = threadIdx.x;
    int bid = blockIdx.x;
    if (bid < NE / 256) {
        int e = bid * 256 + tid;
        atomicAdd(&degi[edst[e]], 1);
    } else if (bid < NE / 256 + NN / 256) {
        int v = (bid - NE / 256) * 256 + tid;
        atomicAdd(&cnt[ndep[v]], 1);
    } else if (bid < NE / 256 + NN / 256 + 448) {
        int flat = (bid - NE / 256 - NN / 256) * 256 + tid;  // < 7*16384
        int g = flat >> 14;
        int rem = flat & 16383;
        int k = rem >> 7, n = rem & 127;
        const float* src;
        if (g == 0) src = W2;
        else if (g == 1) src = Wm1;
        else if (g == 2) src = Wm2;
        else if (g == 3) src = Wtm;
        else if (g == 4) src = Wsm;
        else if (g == 5) src = Wi1;
        else src = Wi1 + 128 * HD;
        wt7[(g << 14) + n * 128 + k] = __float2bfloat16(src[rem]);
    } else {
        int j = tid & 127;
        const float* W = (tid < 128) ? (Wm1 + HD * HD) : (Wi1 + 2 * HD * HD);
        float A0 = 0.f, A1 = 0.f, A2 = 0.f, A3 = 0.f;
        for (int k = 0; k < ZD; k += 4) {
            A0 = fmaf(z[k],     W[(k    ) * HD + j], A0);
            A1 = fmaf(z[k + 1], W[(k + 1) * HD + j], A1);
            A2 = fmaf(z[k + 2], W[(k + 2) * HD + j], A2);
            A3 = fmaf(z[k + 3], W[(k + 3) * HD + j], A3);
        }
        float r = (A0 + A1) + (A2 + A3);
        if (tid < 128) cz1[j] = r + bm1[j];
        else           cz2[j] = r + bi1[j];
    }
}

// ONE block: CSR offsets (+cursor), inv = rsqrt(deg+1), agg2 self term,
// plus (tid 0) the 64-bucket depth scan -> bofs/dcur.
__global__ __launch_bounds__(256) void k_prefix(const int* __restrict__ degi,
                                                const int* __restrict__ cnt,
                                                const float* __restrict__ x,
                                                float* inv, float* agg2,
                                                int* offs, int* cursor,
                                                int* bofs, int* dcur) {
    __shared__ int part[256];
    int tid = threadIdx.x;
    int base = tid * 48;  // 256*48 = 12288
    int s = 0;
    for (int k = 0; k < 48; ++k) s += degi[base + k];
    part[tid] = s;
    __syncthreads();
    for (int off = 1; off < 256; off <<= 1) {
        int v = (tid >= off) ? part[tid - off] : 0;
        __syncthreads();
        part[tid] += v;
        __syncthreads();
    }
    int run = part[tid] - s;  // exclusive
    for (int k = 0; k < 48; ++k) {
        int i = base + k;
        int d = degi[i];
        offs[i] = run;
        cursor[i] = run;
        run += d;
        float iv = rsqrtf((float)(d + 1));
        inv[i] = iv;
        float w = iv * iv;
        agg2[2 * i]     = x[2 * i] * w;
        agg2[2 * i + 1] = x[2 * i + 1] * w;
    }
    if (tid == 255) offs[NN] = run;
    if (tid == 0) {  // depth-bucket exclusive scan (64 serial adds)
        int r = 0;
        for (int d = 0; d < 64; ++d) {
            bofs[d] = r;
            dcur[d] = r;
            r += cnt[d];
        }
        bofs[64] = r;
    }
}

// Split grid: blocks [0,768) bucket edges; [768,816) depth-sort scatter.
__global__ __launch_bounds__(256) void k_bucket_scatter(
        const int* __restrict__ esrc, const int* __restrict__ edst,
        const int* __restrict__ ndep, const float* __restrict__ inv,
        int* cursor, int* ebsrc, float* ebw,
        int* dcur, int* sidx, int* sdep, int* prank) {
    int tid = threadIdx.x;
    if (blockIdx.x < NE / 256) {
        int e = blockIdx.x * 256 + tid;
        int u = esrc[e], v = edst[e];
        int pos = atomicAdd(&cursor[v], 1);
        ebsrc[pos] = u;
        ebw[pos] = inv[u] * inv[v];
    } else {
        int v = (blockIdx.x - NE / 256) * 256 + tid;
        int d = ndep[v];
        int p = atomicAdd(&dcur[d], 1);
        sidx[p] = v;
        sdep[p] = d;
        prank[v] = p;
    }
}

// Layer-1 aggregation, gather form, 4x-unrolled (latency hiding).
__global__ __launch_bounds__(256) void k_gather2(const int* __restrict__ offs,
                                                 const int* __restrict__ ebsrc,
                                                 const float* __restrict__ ebw,
                                                 const float* __restrict__ x,
                                                 float* agg2) {
    int v = blockIdx.x * 256 + threadIdx.x;
    float ax = agg2[2 * v], ay = agg2[2 * v + 1];
    int b = offs[v], e = offs[v + 1];
    const float2* X2 = (const float2*)x;
    int k = b;
    for (; k + 4 <= e; k += 4) {
        int u0 = ebsrc[k], u1 = ebsrc[k + 1], u2 = ebsrc[k + 2], u3 = ebsrc[k + 3];
        float w0 = ebw[k], w1 = ebw[k + 1], w2 = ebw[k + 2], w3 = ebw[k + 3];
        float2 x0 = X2[u0], x1 = X2[u1], x2 = X2[u2], x3 = X2[u3];
        ax = fmaf(x0.x, w0, ax); ay = fmaf(x0.y, w0, ay);
        ax = fmaf(x1.x, w1, ax); ay = fmaf(x1.y, w1, ay);
        ax = fmaf(x2.x, w2, ax); ay = fmaf(x2.y, w2, ay);
        ax = fmaf(x3.x, w3, ax); ay = fmaf(x3.y, w3, ay);
    }
    for (; k < e; ++k) {
        int u = ebsrc[k];
        float w = ebw[k];
        float2 xv = X2[u];
        ax = fmaf(xv.x, w, ax);
        ay = fmaf(xv.y, w, ay);
    }
    agg2[2 * v] = ax;
    agg2[2 * v + 1] = ay;
}

// h1 (bf16) = relu(agg2 @ W1 + b1); seed aggH with layer-2 self-loop term.
__global__ __launch_bounds__(256) void k_lin1(const float* __restrict__ agg2,
                                              const float* __restrict__ W1,
                                              const float* __restrict__ b1,
                                              const float* __restrict__ inv,
                                              unsigned short* h1b, float* aggH) {
    int t = blockIdx.x * 256 + threadIdx.x;
    int v = t >> 7, j = t & 127;
    float hv = fmaxf(fmaf(agg2[2 * v], W1[j],
                     fmaf(agg2[2 * v + 1], W1[HD + j], b1[j])), 0.f);
    h1b[t] = f2bf(hv);
    float iv = inv[v];
    aggH[t] = hv * iv * iv;
}

// Layer-2 aggregation: one WAVE per node, bf16 rows, 4x-unrolled.
__global__ __launch_bounds__(256) void k_gatherH(const int* __restrict__ offs,
                                                 const int* __restrict__ ebsrc,
                                                 const float* __restrict__ ebw,
                                                 const unsigned short* __restrict__ h1b,
                                                 float* aggH) {
    int tid = threadIdx.x;
    int lane = tid & 63;
    int v = blockIdx.x * 4 + (tid >> 6);
    const unsigned* H1 = (const unsigned*)h1b;
    float2* A2 = (float2*)aggH;
    float2 acc = A2[(size_t)v * 64 + lane];
    int b = offs[v], e = offs[v + 1];
    int k = b;
    for (; k + 4 <= e; k += 4) {
        int u0 = ebsrc[k], u1 = ebsrc[k + 1], u2 = ebsrc[k + 2], u3 = ebsrc[k + 3];
        float w0 = ebw[k], w1 = ebw[k + 1], w2 = ebw[k + 2], w3 = ebw[k + 3];
        unsigned hb0 = H1[(size_t)u0 * 64 + lane];
        unsigned hb1 = H1[(size_t)u1 * 64 + lane];
        unsigned hb2 = H1[(size_t)u2 * 64 + lane];
        unsigned hb3 = H1[(size_t)u3 * 64 + lane];
        acc.x = fmaf(__builtin_bit_cast(float, hb0 << 16), w0, acc.x);
        acc.y = fmaf(__builtin_bit_cast(float, hb0 & 0xFFFF0000u), w0, acc.y);
        acc.x = fmaf(__builtin_bit_cast(float, hb1 << 16), w1, acc.x);
        acc.y = fmaf(__builtin_bit_cast(float, hb1 & 0xFFFF0000u), w1, acc.y);
        acc.x = fmaf(__builtin_bit_cast(float, hb2 << 16), w2, acc.x);
        acc.y = fmaf(__builtin_bit_cast(float, hb2 & 0xFFFF0000u), w2, acc.y);
        acc.x = fmaf(__builtin_bit_cast(float, hb3 << 16), w3, acc.x);
        acc.y = fmaf(__builtin_bit_cast(float, hb3 & 0xFFFF0000u), w3, acc.y);
    }
    for (; k < e; ++k) {
        int u = ebsrc[k];
        float w = ebw[k];
        unsigned hb = H1[(size_t)u * 64 + lane];
        acc.x = fmaf(__builtin_bit_cast(float, hb << 16), w, acc.x);
        acc.y = fmaf(__builtin_bit_cast(float, hb & 0xFFFF0000u), w, acc.y);
    }
    A2[(size_t)v * 64 + lane] = acc;
}

// ===== Fused 7-GEMM MLP chain on MFMA (r10-proven; ht/hs scatter to sorted
// row positions via prank) =====
#define AFRAGS(BUF) \
    s8v a0_ = __builtin_bit_cast(s8v, (BUF)[lane16 * 16 + ((quad     ) ^ lane16)]); \
    s8v a1_ = __builtin_bit_cast(s8v, (BUF)[lane16 * 16 + ((quad +  4) ^ lane16)]); \
    s8v a2_ = __builtin_bit_cast(s8v, (BUF)[lane16 * 16 + ((quad +  8) ^ lane16)]); \
    s8v a3_ = __builtin_bit_cast(s8v, (BUF)[lane16 * 16 + ((quad + 12) ^ lane16)]);

#define NBACC(WT4, NCOL, ACC) \
    f4v ACC = (f4v){0.f, 0.f, 0.f, 0.f}; \
    ACC = __builtin_amdgcn_mfma_f32_16x16x32_bf16(a0_, __builtin_bit_cast(s8v, (WT4)[(NCOL) * 16 + quad     ]), ACC, 0, 0, 0); \
    ACC = __builtin_amdgcn_mfma_f32_16x16x32_bf16(a1_, __builtin_bit_cast(s8v, (WT4)[(NCOL) * 16 + quad +  4]), ACC, 0, 0, 0); \
    ACC = __builtin_amdgcn_mfma_f32_16x16x32_bf16(a2_, __builtin_bit_cast(s8v, (WT4)[(NCOL) * 16 + quad +  8]), ACC, 0, 0, 0); \
    ACC = __builtin_amdgcn_mfma_f32_16x16x32_bf16(a3_, __builtin_bit_cast(s8v, (WT4)[(NCOL) * 16 + quad + 12]), ACC, 0, 0, 0);

#define BST(EXPR, RR, COL, USPTR) { int rw_ = quad * 4 + (RR); int cc_ = (COL) >> 3; \
    (USPTR)[rw_ * 128 + (((cc_ ^ rw_)) << 3) + ((COL) & 7)] = f2bf(EXPR); }

#define LDS4R(ACC, B, COL, US) \
    BST(fmaxf(ACC[0] + (B), 0.f), 0, COL, US) BST(fmaxf(ACC[1] + (B), 0.f), 1, COL, US) \
    BST(fmaxf(ACC[2] + (B), 0.f), 2, COL, US) BST(fmaxf(ACC[3] + (B), 0.f), 3, COL, US)

#define LDS4(ACC, B, COL, US) \
    BST(ACC[0] + (B), 0, COL, US) BST(ACC[1] + (B), 1, COL, US) \
    BST(ACC[2] + (B), 2, COL, US) BST(ACC[3] + (B), 3, COL, US)

#define GBF4S(ACC, COL, PTR) \
    ((unsigned short*)(PTR))[(size_t)pr0 * HD + (COL)] = f2bf(ACC[0]); \
    ((unsigned short*)(PTR))[(size_t)pr1 * HD + (COL)] = f2bf(ACC[1]); \
    ((unsigned short*)(PTR))[(size_t)pr2 * HD + (COL)] = f2bf(ACC[2]); \
    ((unsigned short*)(PTR))[(size_t)pr3 * HD + (COL)] = f2bf(ACC[3]);

#define GF4(ACC, B, COL, PTR) \
    (PTR)[(size_t)(r0 + quad * 4 + 0) * HD + (COL)] = ACC[0] + (B); \
    (PTR)[(size_t)(r0 + quad * 4 + 1) * HD + (COL)] = ACC[1] + (B); \
    (PTR)[(size_t)(r0 + quad * 4 + 2) * HD + (COL)] = ACC[2] + (B); \
    (PTR)[(size_t)(r0 + quad * 4 + 3) * HD + (COL)] = ACC[3] + (B);

__global__ __launch_bounds__(256) void k_mlp7_mfma(
        const float* __restrict__ s1in, const __hip_bfloat16* __restrict__ wt7,
        const float* __restrict__ bb2, const float* __restrict__ bcz1,
        const float* __restrict__ bbm2, const float* __restrict__ bcz2,
        const int* __restrict__ prank,
        float* __restrict__ outA, float* __restrict__ outB,
        __hip_bfloat16* __restrict__ htb, __hip_bfloat16* __restrict__ hsb) {
    __shared__ float4 bufA4[256];  // 16 rows x 16 chunks (bf16x8) = 4 KB
    __shared__ float4 bufB4[256];
    int tid = threadIdx.x;
    int wv = tid >> 6;
    int l = tid & 63;
    int lane16 = l & 15;
    int quad = l >> 4;
    int r0 = blockIdx.x * 16;
    const float4* wt4 = (const float4*)wt7;

    int pr0 = prank[r0 + quad * 4 + 0];
    int pr1 = prank[r0 + quad * 4 + 1];
    int pr2 = prank[r0 + quad * 4 + 2];
    int pr3 = prank[r0 + quad * 4 + 3];

    {
        const float4* g4 = (const float4*)(s1in + (size_t)r0 * HD);
        float4 u0 = g4[2 * tid], u1 = g4[2 * tid + 1];
        int row_ = tid >> 4, c_ = tid & 15;
        bufA4[row_ * 16 + (c_ ^ row_)] = pack8(u0, u1);
    }
    __syncthreads();
    int col0 = wv * 32 + lane16, col1 = col0 + 16;
    unsigned short* usA = (unsigned short*)bufA4;
    unsigned short* usB = (unsigned short*)bufB4;

    {   // G1: h2 = relu(aggH @ W2 + b2) -> bufB
        AFRAGS(bufA4)
        NBACC(wt4, col0, cA) NBACC(wt4, col1, cB)
        float q0 = bb2[col0], q1 = bb2[col1];
        LDS4R(cA, q0, col0, usB) LDS4R(cB, q1, col1, usB)
    }
    __syncthreads();
    {   // G2: t = relu(h2 @ Wm1 + cz1) -> bufA
        AFRAGS(bufB4)
        const float4* wt = wt4 + 2048;
        NBACC(wt, col0, cA) NBACC(wt, col1, cB)
        float q0 = bcz1[col0], q1 = bcz1[col1];
        LDS4R(cA, q0, col0, usA) LDS4R(cB, q1, col1, usA)
    }
    __syncthreads();
    {   // G3: h = t @ Wm2 + bm2 -> bufB
        AFRAGS(bufA4)
        const float4* wt = wt4 + 2 * 2048;
        NBACC(wt, col0, cA) NBACC(wt, col1, cB)
        float q0 = bbm2[col0], q1 = bbm2[col1];
        LDS4(cA, q0, col0, usB) LDS4(cB, q1, col1, usB)
    }
    __syncthreads();
    {   // G4: ht = h @ Wtm -> sorted rows, bf16
        AFRAGS(bufB4)
        const float4* wt = wt4 + 3 * 2048;
        NBACC(wt, col0, cA) NBACC(wt, col1, cB)
        GBF4S(cA, col0, htb) GBF4S(cB, col1, htb)
    }
    {   // G5: hs = h @ Wsm -> sorted rows, bf16
        AFRAGS(bufB4)
        const float4* wt = wt4 + 4 * 2048;
        NBACC(wt, col0, cA) NBACC(wt, col1, cB)
        GBF4S(cA, col0, hsb) GBF4S(cB, col1, hsb)
    }
    {   // G6: A = h @ Wi1[:128] -> global f32 (original order)
        AFRAGS(bufB4)
        const float4* wt = wt4 + 5 * 2048;
        NBACC(wt, col0, cA) NBACC(wt, col1, cB)
        GF4(cA, 0.f, col0, outA) GF4(cB, 0.f, col1, outA)
    }
    {   // G7: B = h @ Wi1[128:256] + cz2 -> global f32 (in-place over s1)
        AFRAGS(bufB4)
        const float4* wt = wt4 + 6 * 2048;
        NBACC(wt, col0, cA) NBACC(wt, col1, cB)
        float q0 = bcz2[col0], q1 = bcz2[col1];
        GF4(cA, q0, col0, outB) GF4(cB, q1, col1, outB)
    }
}

// ===== Fused bf16-MFMA scores + masked top-2, v8.3 =====
// r15-proven even-split + parity fix; heavy row-blocks first (reversed
// blockIdx.x) for makespan. pv stores packed scores only.
#define STG(buf, q, val) { int r_ = (q) >> 4, c_ = (q) & 15; \
    (buf)[r_ * 16 + (c_ ^ (r_ & 7))] = (val); }

#define DO_KC(kc, AR) { \
    int co_ = (kc) * 4 + quad; \
    int bo_ = bbase + (co_ ^ brm); \
    acc0 = __builtin_amdgcn_mfma_f32_16x16x32_bf16(AR, __builtin_bit_cast(s8v, B[bo_      ]), acc0, 0, 0, 0); \
    acc1 = __builtin_amdgcn_mfma_f32_16x16x32_bf16(AR, __builtin_bit_cast(s8v, B[bo_ + 256]), acc1, 0, 0, 0); \
    acc2 = __builtin_amdgcn_mfma_f32_16x16x32_bf16(AR, __builtin_bit_cast(s8v, B[bo_ + 512]), acc2, 0, 0, 0); \
    acc3 = __builtin_amdgcn_mfma_f32_16x16x32_bf16(AR, __builtin_bit_cast(s8v, B[bo_ + 768]), acc3, 0, 0, 0); }

#define ROW_MERGE(r, accel) { \
    unsigned pb_ = (__builtin_bit_cast(unsigned, accel) & 0xFFFFC000u) | e_; \
    float sf_ = __builtin_bit_cast(float, (du_ < dvr##r) ? pb_ : negp_); \
    k2_##r = __builtin_amdgcn_fmed3f(k1_##r, k2_##r, sf_); \
    k1_##r = fmaxf(k1_##r, sf_); }

#define DO_MERGE(nb, accv) { \
    int p_ = u0 + (nb) * 16 + lane16; \
    int du_ = sdep[p_]; \
    unsigned e_ = 0x3FFFu - (unsigned)sidx[p_]; \
    unsigned negp_ = negbase | e_; \
    ROW_MERGE(0, accv[0]) ROW_MERGE(1, accv[1]) \
    ROW_MERGE(2, accv[2]) ROW_MERGE(3, accv[3]) }

#define BF(r, m) { \
    float o1_ = __shfl_xor(k1_##r, m, 64); \
    float o2_ = __shfl_xor(k2_##r, m, 64); \
    float m2_ = fmaxf(k2_##r, o2_); \
    k2_##r = __builtin_amdgcn_fmed3f(k1_##r, o1_, m2_); \
    k1_##r = fmaxf(k1_##r, o1_); }

#define EMITR(r, GROW) { \
    size_t o = ((size_t)seg * NN + (GROW)) * 2; \
    pv[o] = k1_##r; pv[o + 1] = k2_##r; }

__global__ __launch_bounds__(256) void k_score_top2_mfma(
        const __hip_bfloat16* __restrict__ htb,
        const __hip_bfloat16* __restrict__ hsb,
        const int* __restrict__ sdep, const int* __restrict__ sidx,
        const int* __restrict__ bofs,
        float* __restrict__ pv) {
    __shared__ float4 Bs4[2][64 * 16];   // 32 KB double buffer (B only)
    int tid = threadIdx.x;
    int w = tid >> 6;
    int l = tid & 63;
    int lane16 = l & 15;
    int quad = l >> 4;
    int rb = (int)gridDim.x - 1 - (int)blockIdx.x;  // heavy blocks first
    int row0 = rb * 64;
    int seg = blockIdx.y;
    const unsigned negbase = __builtin_bit_cast(unsigned, NEGV) & 0xFFFFC000u;

    // even-split of this row-block's valid candidate prefix
    int dmax = sdep[row0 + 63];
    int lim = bofs[dmax];
    int nt = (lim + 63) >> 6;               // total tiles, <= 192
    int t0 = (seg * nt) >> 4;
    int t1 = ((seg + 1) * nt) >> 4;

    // A fragments: named registers, loaded once (sorted target rows).
    s8v ar0, ar1, ar2, ar3;
    {
        const float4* ga = (const float4*)(htb + (size_t)(row0 + w * 16 + lane16) * HD);
        ar0 = __builtin_bit_cast(s8v, ga[quad]);
        ar1 = __builtin_bit_cast(s8v, ga[4 + quad]);
        ar2 = __builtin_bit_cast(s8v, ga[8 + quad]);
        ar3 = __builtin_bit_cast(s8v, ga[12 + quad]);
    }
    if (t0 < t1) {   // stage first tile into the parity-matching buffer
        float4* B0 = Bs4[t0 & 1];
        const float4* gb = (const float4*)(hsb + (size_t)(t0 * 64) * HD);
        float4 b0_ = gb[tid], b1_ = gb[tid + 256], b2_ = gb[tid + 512], b3_ = gb[tid + 768];
        STG(B0, tid, b0_) STG(B0, tid + 256, b1_)
        STG(B0, tid + 512, b2_) STG(B0, tid + 768, b3_)
    }

    int bbase = lane16 * 16, brm = lane16 & 7;

    int dvr0 = sdep[row0 + w * 16 + quad * 4 + 0];
    int dvr1 = sdep[row0 + w * 16 + quad * 4 + 1];
    int dvr2 = sdep[row0 + w * 16 + quad * 4 + 2];
    int dvr3 = sdep[row0 + w * 16 + quad * 4 + 3];

    // defaults: packed NEGV for orig u=0 (k1) and u=1 (k2), lane16==0 only.
    float ki1 = (lane16 == 0) ? __builtin_bit_cast(float, negbase | 0x3FFFu) : -3.4e38f;
    float ki2 = (lane16 == 0) ? __builtin_bit_cast(float, negbase | 0x3FFEu) : -3.4e38f;
    float k1_0 = ki1, k1_1 = ki1, k1_2 = ki1, k1_3 = ki1;
    float k2_0 = ki2, k2_1 = ki2, k2_2 = ki2, k2_3 = ki2;

    float4 p0, p1, p2, p3;
    for (int t = t0; t < t1; ++t) {
        int u0 = t * 64;
        __syncthreads();
        if (t + 1 < t1) {
            const float4* g = (const float4*)(hsb + (size_t)(u0 + 64) * HD);
            p0 = g[tid]; p1 = g[tid + 256]; p2 = g[tid + 512]; p3 = g[tid + 768];
        }
        const float4* B = Bs4[t & 1];
        f4v acc0 = (f4v){0.f, 0.f, 0.f, 0.f};
        f4v acc1 = (f4v){0.f, 0.f, 0.f, 0.f};
        f4v acc2 = (f4v){0.f, 0.f, 0.f, 0.f};
        f4v acc3 = (f4v){0.f, 0.f, 0.f, 0.f};
        DO_KC(0, ar0) DO_KC(1, ar1) DO_KC(2, ar2) DO_KC(3, ar3)
        DO_MERGE(0, acc0) DO_MERGE(1, acc1) DO_MERGE(2, acc2) DO_MERGE(3, acc3)
        if (t + 1 < t1) {
            float4* Bn = Bs4[(t + 1) & 1];
            STG(Bn, tid, p0) STG(Bn, tid + 256, p1)
            STG(Bn, tid + 512, p2) STG(Bn, tid + 768, p3)
        }
    }

    BF(0, 1) BF(1, 1) BF(2, 1) BF(3, 1)
    BF(0, 2) BF(1, 2) BF(2, 2) BF(3, 2)
    BF(0, 4) BF(1, 4) BF(2, 4) BF(3, 4)
    BF(0, 8) BF(1, 8) BF(2, 8) BF(3, 8)

    if (lane16 == 0) {
        int g0 = sidx[row0 + w * 16 + quad * 4 + 0];
        int g1 = sidx[row0 + w * 16 + quad * 4 + 1];
        int g2 = sidx[row0 + w * 16 + quad * 4 + 2];
        int g3 = sidx[row0 + w * 16 + quad * 4 + 3];
        EMITR(0, g0) EMITR(1, g1) EMITR(2, g2) EMITR(3, g3)
    }
}

// ONE kernel writes ALL outputs (f32): parallel packed merge (r15-proven).
__global__ __launch_bounds__(256) void k_final(const float* __restrict__ pv,
                                               const int* __restrict__ ntype,
                                               const int* __restrict__ ndepth,
                                               const float* __restrict__ A,
                                               const float* __restrict__ B,
                                               const float* __restrict__ Wi2,
                                               const float* __restrict__ bi2,
                                               float* __restrict__ out) {
    int tid = threadIdx.x;
    int lane = tid & 63;
    int v = blockIdx.x * 4 + (tid >> 6);

    float k1 = -3.4e38f;
    if (lane < 32) {
        k1 = pv[((size_t)(lane >> 1) * NN + v) * 2 + (lane & 1)];
    }
    float k2 = -3.4e38f;
#pragma unroll
    for (int m = 1; m <= 16; m <<= 1) {
        float o1 = __shfl_xor(k1, m, 64);
        float o2 = __shfl_xor(k2, m, 64);
        float m2 = fmaxf(k2, o2);
        k2 = __builtin_amdgcn_fmed3f(k1, o1, m2);
        k1 = fmaxf(k1, o1);
    }
    float K1 = __shfl(k1, 0, 64);
    float K2 = __shfl(k2, 0, 64);
    unsigned b1 = __builtin_bit_cast(unsigned, K1);
    unsigned b2 = __builtin_bit_cast(unsigned, K2);
    int I1 = 0x3FFF - (int)(b1 & 0x3FFFu);
    int I2 = 0x3FFF - (int)(b2 & 0x3FFFu);

    if (lane == 0) {
        int tp = ntype[v];
        bool tv = (tp != 0) && (ndepth[v] > 0) && (K1 > -5.0e8f);  // NEG/2
        out[2 * NN + 2 * v]     = K1;
        out[2 * NN + 2 * v + 1] = K2;
        out[4 * NN + 2 * v]     = (float)I1;
        out[4 * NN + 2 * v + 1] = (float)I2;
        out[6 * NN + 2 * v]     = tv ? 1.f : 0.f;
        out[6 * NN + 2 * v + 1] = (tv && tp == 2) ? 1.f : 0.f;
    }

    int u1 = min(max(I1, 0), NN - 1);
    int u2 = min(max(I2, 0), NN - 1);
    const float2* A2p = (const float2*)A;
    float2 av1 = A2p[(size_t)u1 * 64 + lane];
    float2 av2 = A2p[(size_t)u2 * 64 + lane];
    float2 bv = ((const float2*)B)[(size_t)v * 64 + lane];
    float2 wv = ((const float2*)Wi2)[lane];
    float bias = bi2[0];
    float a1 = fmaf(fmaxf(av1.x + bv.x, 0.f), wv.x,
                    fmaxf(av1.y + bv.y, 0.f) * wv.y);
    float a2 = fmaf(fmaxf(av2.x + bv.x, 0.f), wv.x,
                    fmaxf(av2.y + bv.y, 0.f) * wv.y);
#pragma unroll
    for (int off = 32; off > 0; off >>= 1) {
        a1 += __shfl_down(a1, off);
        a2 += __shfl_down(a2, off);
    }
    if (lane == 0) {
        out[2 * v]     = 1.f / (1.f + expf(-(a1 + bias)));
        out[2 * v + 1] = 1.f / (1.f + expf(-(a2 + bias)));
    }
}

extern "C" void kernel_launch(void* const* d_in, const int* in_sizes, int n_in,
                              void* d_out, int out_size, void* d_ws, size_t ws_size,
                              hipStream_t stream) {
    (void)in_sizes; (void)n_in; (void)out_size; (void)ws_size;
    const float* x   = (const float*)d_in[0];
    const float* z   = (const float*)d_in[1];
    const int* ntype = (const int*)d_in[2];
    const int* ndep  = (const int*)d_in[3];
    const int* eidx  = (const int*)d_in[4];
    const float* W1  = (const float*)d_in[5];
    const float* b1  = (const float*)d_in[6];
    const float* W2  = (const float*)d_in[7];
    const float* b2  = (const float*)d_in[8];
    const float* Wm1 = (const float*)d_in[9];
    const float* bm1 = (const float*)d_in[10];
    const float* Wm2 = (const float*)d_in[11];
    const float* bm2 = (const float*)d_in[12];
    const float* Wsm = (const float*)d_in[13];
    const float* Wtm = (const float*)d_in[14];
    const float* Wi1 = (const float*)d_in[15];
    const float* bi1 = (const float*)d_in[16];
    const float* Wi2 = (const float*)d_in[17];
    const float* bi2 = (const float*)d_in[18];
    float* out = (float*)d_out;

    const int* esrc = eidx;
    const int* edst = eidx + NE;

    // Workspace layout (~24.5 MiB).
    const size_t S2N = (size_t)SEG * 2 * NN;  // 393216
    float* ws = (float*)d_ws;
    float* pv     = ws;                       // [S2N] f (packed scores)
    int*   pi     = (int*)(pv + S2N);         // [S2N] i (spacer)
    int*   degi   = pi + S2N;                 // [NN]   (memset with cnt)
    int*   cnt    = degi + NN;                // [64]
    float* inv    = (float*)(cnt + 64);       // [NN]
    float* agg2   = inv + NN;                 // [2NN]
    float* cz1    = agg2 + 2 * NN;            // [128]
    float* cz2    = cz1 + 128;                // [128]
    int*   offs   = (int*)(cz2 + 128);        // [NN+16]
    int*   cursor = offs + NN + 16;           // [NN]
    int*   bofs   = cursor + NN;              // [80]
    int*   dcur   = bofs + 80;                // [64]
    int*   sidx   = dcur + 64;                // [NN]
    int*   sdep   = sidx + NN;                // [NN]
    int*   prank  = sdep + NN;                // [NN]
    int*   ebsrc  = prank + NN;               // [NE]
    float* ebw    = (float*)(ebsrc + NE);     // [NE]
    __hip_bfloat16* wt7 = (__hip_bfloat16*)(ebw + NE);  // [7*16384] bf16
    size_t F = (size_t)NN * HD;
    float* s0 = (float*)(wt7 + 7 * 16384);    // h1b (bf16) -> {htb_s, hsb_s}
    float* s1 = s0 + F;                       // aggH -> B (in-place)
    float* s2 = s1 + F;                       // A
    unsigned short* h1b = (unsigned short*)s0;
    __hip_bfloat16* htb = (__hip_bfloat16*)s0;
    __hip_bfloat16* hsb = htb + F;

    hipMemsetAsync(degi, 0, (NN + 64) * sizeof(int), stream);
    k_counts_wz<<<NE / 256 + NN / 256 + 448 + 1, 256, 0, stream>>>(
        edst, ndep, W2, Wm1, Wm2, Wtm, Wsm, Wi1, z, bm1, bi1,
        degi, cnt, wt7, cz1, cz2);
    k_prefix<<<1, 256, 0, stream>>>(degi, cnt, x, inv, agg2, offs, cursor, bofs, dcur);
    k_bucket_scatter<<<NE / 256 + NN / 256, 256, 0, stream>>>(
        esrc, edst, ndep, inv, cursor, ebsrc, ebw, dcur, sidx, sdep, prank);
    k_gather2<<<NN / 256, 256, 0, stream>>>(offs, ebsrc, ebw, x, agg2);
    k_lin1<<<NN * HD / 256, 256, 0, stream>>>(agg2, W1, b1, inv, h1b, s1);
    k_gatherH<<<NN / 4, 256, 0, stream>>>(offs, ebsrc, ebw, h1b, s1);
    k_mlp7_mfma<<<NN / 16, 256, 0, stream>>>(s1, wt7, b2, cz1, bm2, cz2,
                                             prank, s2, s1, htb, hsb);
    k_score_top2_mfma<<<dim3(NN / 64, SEG), 256, 0, stream>>>(
        htb, hsb, sdep, sidx, bofs, pv);
    k_final<<<NN / 4, 256, 0, stream>>>(pv, ntype, ndep, s2, s1, Wi2, bi2, out);
}